// Round 13
// baseline (3713.950 us; speedup 1.0000x reference)
//
#include <hip/hip_runtime.h>
#include <hip/hip_bf16.h>
#include <math.h>

// Problem constants
#define VV   32000
#define DD   300
#define HU   300
#define NC   3
#define BB   128
#define TT   512
#define N4H  1200
#define CHUNK 64
#define NCHUNK (TT / CHUNK)

// Recurrent kernel partition
#define GC   15   // col groups (units)
#define GR   16   // row groups
#define RPW  8    // rows per WG (BB/GR)
#define UPW  20   // units per WG (HU/GC)
#define KSW  96   // k-window per wave (4 waves x 96 covers 300 w/ zero pad)
#define HLB_STRIDE 312            // h plane row stride in shorts (624B: 16B-aligned, 2-way bank alias = free)
#define HLB_SIZE   (16 * HLB_STRIDE + 32)

// Workspace layout: [ex (ulong, tagged h exchange)][cst][hfin]  (zx deleted: x-GEMM fused)
static constexpr size_t EX_W   = (size_t)2 * GR * RPW * HU;  // 76,800 ulongs
static constexpr size_t CST_F  = (size_t)BB * HU;            // 38,400 floats
static constexpr size_t HFIN_F = (size_t)BB * HU;            // 38,400 floats

typedef __attribute__((ext_vector_type(8))) short bf16x8;
typedef __attribute__((ext_vector_type(8))) _Float16 f16x8;
typedef __attribute__((ext_vector_type(4))) float f32x4;
typedef unsigned long long ull;

__device__ __forceinline__ short f2bf(float f) {
    unsigned u = __float_as_uint(f);
    u += 0x7fff + ((u >> 16) & 1);   // round-to-nearest-even
    return (short)(u >> 16);
}
__device__ __forceinline__ short f2h(float f) {   // float -> f16 bits (RTNE)
    _Float16 h = (_Float16)f;
    return *(short*)&h;
}
__device__ __forceinline__ float h2f(short s) {
    _Float16 h = *(_Float16*)&s;
    return (float)h;
}
__device__ __forceinline__ float sigm(float x) { return 1.f / (1.f + __expf(-x)); }
__device__ __forceinline__ float tanh_(float x) { return 1.f - 2.f / (__expf(2.f * x) + 1.f); }

// ---------------------------------------------------------------------------
// init: zero exchange tags, c state, out[0]  (ws is poisoned 0xAA every launch)
// ---------------------------------------------------------------------------
__global__ void init_kernel(ull* __restrict__ ex, float* __restrict__ cst,
                            float* __restrict__ out) {
    size_t i = (size_t)blockIdx.x * 256 + threadIdx.x;
    if (i < EX_W) ex[i] = 0ull;
    if (i < CST_F) cst[i] = 0.f;
    if (i == 0) out[0] = 0.f;
}

// ---------------------------------------------------------------------------
// Persistent recurrent kernel with FUSED x-GEMM. 240 WGs = 16 rg x 15 cg.
//
// z_t = x_t @ Wx (bf16 MFMA, fused — was the separate zx_gemm kernel)
//     + (h_hi + h_lo) @ Wh_f16 (f16 MFMA, h-side split; absmax at 4.88e-4)
//     + bias (gate-lane registers)
//
// R13 fusion: per step each wave gathers its x A-fragments (8 real rows x its
// 96-col K-window) straight from emb into REGISTERS — 6 dwordx4 issued BEFORE
// the h-poll, so the gather latency hides in the wait slack. x-part adds 15
// bf16 MFMAs into the same accumulator. Wx fragments live in LDS like Wh
// (+60 KB). To fit 160 KB, zp loses its parity buffer -> 2 barriers/step
// (R11 measured 1-vs-2 barriers ~neutral). Deletes: zx buffer, 8 zx_gemm
// dispatches, z_pre global reads (~280 us of serial non-rec time).
//
// Sync protocol unchanged (R12): fire-and-forget tagged words
// (tag<<32|f32 h), relaxed agent-scope atomics, per-wave K-window stripes,
// sentinel-gated batched polling. Tag-ABA safety: publish(s+2) > barrier(s+1)
// > all 4 waves detected tags s+1 over window-union = all 15 producers'
// s+1 publishes >= every consumer's step-s reads.
//
// NaN guard (R6): h planes zeroed IN FULL once per dispatch (wave 3 A-reads
// of cols 300..319 are exact 0; B=0 there; 0*0=0). x-frags: pad rows m>=8
// are register zeros; wave-3 k>=300 lanes guarded (no OOB emb reads, zeros).
// Cross-row LDS alias reads (cols 312..319 = next row's 0..7) are finite
// f16 mid-write values x B=0 -> contribute exact 0 (same as R11/R12).
// ---------------------------------------------------------------------------
__global__ __launch_bounds__(256, 1) void lstm_rec(
    const float* __restrict__ emb, const int* __restrict__ ids,
    const float* __restrict__ Wl, const float* __restrict__ bl,
    const int* __restrict__ lens, ull* __restrict__ ex,
    float* __restrict__ cst, float* __restrict__ hfin, int t0)
{
    const int tid = threadIdx.x;
    const int wv  = tid >> 6, ln = tid & 63;
    const int rg  = blockIdx.x % GR;
    const int cgi = blockIdx.x / GR;
    const int r0  = rg * RPW;
    const int u0  = cgi * UPW;
    const int m   = ln & 15;           // MFMA row / col-in-tile
    const int quad = ln >> 4;

    // producers overlapping wave wv's K-window [96wv, 96wv+96)
    const int pstart_tbl[4] = {0, 4, 9, 14};
    const int np_tbl[4]     = {5, 6, 6, 1};
    const int pstart = pstart_tbl[wv];
    const int np     = np_tbl[wv];

    __shared__ short h_hi[HLB_SIZE];        // f16 hi plane of h_{t-1}
    __shared__ short h_lo[HLB_SIZE];        // f16 lo plane of h_{t-1}
    __shared__ float zp[4][RPW][84];        // per-wave k-partials (single buf)
    __shared__ short w_l[4 * 15 * 64 * 8];  // f16 W_h fragments, frag-ordered
    __shared__ short w_lx[4 * 15 * 64 * 8]; // bf16 W_x fragments, frag-ordered
    __shared__ int   ids_l[RPW][CHUNK];     // token ids for this chunk

    // ---- one-time: pack W_h (f16) and W_x (bf16) B-fragments into LDS ----
    // B[k=quad*8+j][n=lane&15]; frag f = s*5+nt covers kstep s, ntile nt.
    #pragma unroll
    for (int s = 0; s < 3; ++s) {
        #pragma unroll
        for (int nt = 0; nt < 5; ++nt) {
            int c    = nt * 16 + m;            // 0..79 within WG cols
            int gate = c / 20;
            int wcol = 300 * gate + u0 + (c % 20);
            f16x8 bh;
            bf16x8 bx;
            #pragma unroll
            for (int j = 0; j < 8; ++j) {
                int k = KSW * wv + 32 * s + quad * 8 + j;
                float vh = (k < HU) ? Wl[(size_t)(DD + k) * N4H + wcol] : 0.f;
                float vx = (k < DD) ? Wl[(size_t)k * N4H + wcol] : 0.f;
                bh[j] = (_Float16)vh;
                bx[j] = f2bf(vx);
            }
            int fo = (((wv * 15) + (s * 5 + nt)) * 64 + ln) * 8;
            *(f16x8*)&w_l[fo]  = bh;
            *(bf16x8*)&w_lx[fo] = bx;
        }
    }
    const int nks = (wv == 3) ? 1 : 3;   // wave 3: only kstep 0 has real k

    // zero BOTH h planes in full once per dispatch (NaN guard + h0 = 0)
    for (int i = tid; i < HLB_SIZE; i += 256) { h_hi[i] = 0; h_lo[i] = 0; }

    // stage this chunk's token ids (coalesced per row)
    for (int i = tid; i < RPW * CHUNK; i += 256) {
        int r = i >> 6, tcc = i & 63;
        ids_l[r][tcc] = ids[(size_t)(r0 + r) * TT + t0 + tcc];
    }

    // gate role (tid < 160): u = tid%20, r = tid/20; c/h_old/bias in registers
    const int g_u = tid % UPW, g_r = tid / UPW;
    const bool gl = (tid < RPW * UPW);
    float c_reg = 0.f, ho_reg = 0.f;
    float blr[4] = {0.f, 0.f, 0.f, 0.f};
    int mylen = 0;
    if (gl) {
        c_reg = cst[(size_t)(r0 + g_r) * HU + u0 + g_u];
        mylen = lens[r0 + g_r];
        #pragma unroll
        for (int gg = 0; gg < 4; ++gg) blr[gg] = bl[300 * gg + u0 + g_u];
        if (t0 > 0) {   // reload own h_{t0-1} (tag t0, parity t0&1) from last dispatch
            ull v = __hip_atomic_load(
                ex + (((size_t)(t0 & 1) * GR + rg) * RPW + g_r) * HU + u0 + g_u,
                __ATOMIC_RELAXED, __HIP_MEMORY_SCOPE_AGENT);
            ho_reg = __uint_as_float((unsigned)v);
        }
    }
    __syncthreads();   // packs + zeros + ids visible before first step

    for (int tc = 0; tc < CHUNK; ++tc) {
        const int t = t0 + tc;
        const int par = t & 1;

        // ---- x A-fragments: gather from emb into registers (pre-poll) ----
        bf16x8 xa[3];
        #pragma unroll
        for (int s = 0; s < 3; ++s)
            #pragma unroll
            for (int j = 0; j < 8; ++j) xa[s][j] = 0;
        if (m < RPW) {
            const float* xrow = emb + (size_t)ids_l[m][tc] * DD;
            if (wv < 3) {
                #pragma unroll
                for (int s = 0; s < 3; ++s) {
                    int kb = KSW * wv + 32 * s + quad * 8;   // max 288+? <=280 ok
                    float4 p = *(const float4*)(xrow + kb);
                    float4 q = *(const float4*)(xrow + kb + 4);
                    xa[s][0] = f2bf(p.x); xa[s][1] = f2bf(p.y);
                    xa[s][2] = f2bf(p.z); xa[s][3] = f2bf(p.w);
                    xa[s][4] = f2bf(q.x); xa[s][5] = f2bf(q.y);
                    xa[s][6] = f2bf(q.z); xa[s][7] = f2bf(q.w);
                }
            } else {
                int kb = KSW * 3 + quad * 8;                 // 288..312
                #pragma unroll
                for (int j = 0; j < 8; ++j) {
                    int k = kb + j;
                    xa[0][j] = (k < DD) ? f2bf(xrow[k]) : (short)0;
                }
            }
        }

        // ---- per-wave stage of OWN h K-window stripe (sentinel-gated) ----
        if (t > 0) {
            const ull* exb = ex + ((size_t)par * GR + rg) * (RPW * HU);

            // phase 1: sentinel spin — lane l polls producer pstart+l
            if (ln < np) {
                const ull* sp = exb + (pstart + ln) * UPW;
                while ((int)(__hip_atomic_load(sp, __ATOMIC_RELAXED,
                             __HIP_MEMORY_SCOPE_AGENT) >> 32) < t)
                    __builtin_amdgcn_s_sleep(1);
            }

            // phase 2+3: full stripe pass (typically 1 sweep) + straggler poll
            if (wv < 3) {
                unsigned pend = 0xFFFu;
                do {
                    ull v[12];
                    #pragma unroll
                    for (int k = 0; k < 12; ++k)
                        if ((pend >> k) & 1) {
                            int i = ln + (k << 6);
                            int r = i / 96, u = KSW * wv + (i % 96);
                            v[k] = __hip_atomic_load(exb + r * HU + u,
                                                     __ATOMIC_RELAXED,
                                                     __HIP_MEMORY_SCOPE_AGENT);
                        }
                    unsigned got = 0;
                    #pragma unroll
                    for (int k = 0; k < 12; ++k) {
                        if (((pend >> k) & 1) && (int)(v[k] >> 32) >= t) {
                            int i = ln + (k << 6);
                            int r = i / 96, u = KSW * wv + (i % 96);
                            int idx = r * HLB_STRIDE + u;
                            float f = __uint_as_float((unsigned)v[k]);
                            short hi = f2h(f);
                            h_hi[idx] = hi;
                            h_lo[idx] = f2h(f - h2f(hi));
                            got |= 1u << k;
                        }
                    }
                    pend &= ~got;
                    if (pend) __builtin_amdgcn_s_sleep(1);
                } while (pend);
            } else {
                unsigned pend = (ln < 32) ? 0x3u : 0x1u;
                do {
                    ull v[2];
                    #pragma unroll
                    for (int k = 0; k < 2; ++k)
                        if ((pend >> k) & 1) {
                            int i = ln + (k << 6);
                            int r = i / 12, u = 288 + (i % 12);
                            v[k] = __hip_atomic_load(exb + r * HU + u,
                                                     __ATOMIC_RELAXED,
                                                     __HIP_MEMORY_SCOPE_AGENT);
                        }
                    unsigned got = 0;
                    #pragma unroll
                    for (int k = 0; k < 2; ++k) {
                        if (((pend >> k) & 1) && (int)(v[k] >> 32) >= t) {
                            int i = ln + (k << 6);
                            int r = i / 12, u = 288 + (i % 12);
                            int idx = r * HLB_STRIDE + u;
                            float f = __uint_as_float((unsigned)v[k]);
                            short hi = f2h(f);
                            h_hi[idx] = hi;
                            h_lo[idx] = f2h(f - h2f(hi));
                            got |= 1u << k;
                        }
                    }
                    pend &= ~got;
                    if (pend) __builtin_amdgcn_s_sleep(1);
                } while (pend);
            }
        }

        // ---- MFMA: h (f16 split, LDS A) + x (bf16, register A); B from LDS ----
        f32x4 acc[5];
        #pragma unroll
        for (int nt = 0; nt < 5; ++nt) acc[nt] = (f32x4){0.f, 0.f, 0.f, 0.f};
        for (int s = 0; s < nks; ++s) {
            const int aoff = m * HLB_STRIDE + KSW * wv + 32 * s + quad * 8;
            f16x8 ah = *(const f16x8*)&h_hi[aoff];
            f16x8 al = *(const f16x8*)&h_lo[aoff];
            #pragma unroll
            for (int nt = 0; nt < 5; ++nt) {
                int fo = (((wv * 15) + (s * 5 + nt)) * 64 + ln) * 8;
                f16x8  bh = *(const f16x8*)&w_l[fo];
                bf16x8 bx = *(const bf16x8*)&w_lx[fo];
                acc[nt] = __builtin_amdgcn_mfma_f32_16x16x32_f16(
                    ah, bh, acc[nt], 0, 0, 0);
                acc[nt] = __builtin_amdgcn_mfma_f32_16x16x32_f16(
                    al, bh, acc[nt], 0, 0, 0);
                acc[nt] = __builtin_amdgcn_mfma_f32_16x16x32_bf16(
                    xa[s], bx, acc[nt], 0, 0, 0);
            }
        }
        // C: row=quad*4+reg (lanes 0-31 -> rows 0-7), col=nt*16+m
        if (ln < 32) {
            #pragma unroll
            for (int nt = 0; nt < 5; ++nt)
                #pragma unroll
                for (int r4 = 0; r4 < 4; ++r4)
                    zp[wv][quad * 4 + r4][nt * 16 + m] = acc[nt][r4];
        }
        __syncthreads();   // barrier 1: zp(t) visible to gate lanes

        // ---- reduce 4 partials + bias + gates + tagged publish ----
        if (gl) {
            const int b = r0 + g_r;
            float z4[4];
            #pragma unroll
            for (int gg = 0; gg < 4; ++gg) {
                int cidx = gg * UPW + g_u;
                z4[gg] = blr[gg] + zp[0][g_r][cidx] + zp[1][g_r][cidx]
                                 + zp[2][g_r][cidx] + zp[3][g_r][cidx];
            }
            float ig = sigm(z4[0]);
            float jg = tanh_(z4[1]);
            float fg = sigm(z4[2] + 1.0f);   // FORGET_BIAS
            float og = sigm(z4[3]);
            float c_new = c_reg * fg + ig * jg;
            float h_new = tanh_(c_new) * og;
            bool upd = (t < mylen);
            ho_reg = upd ? h_new : ho_reg;
            c_reg  = upd ? c_new : c_reg;
            // publish h_t (tag t+1, parity (t+1)&1) — fire & forget
            ull pk = ((ull)(unsigned)(t + 1) << 32) | (ull)__float_as_uint(ho_reg);
            __hip_atomic_store(
                ex + (((size_t)((t + 1) & 1) * GR + rg) * RPW + g_r) * HU + u0 + g_u,
                pk, __ATOMIC_RELAXED, __HIP_MEMORY_SCOPE_AGENT);
            if (tc == CHUNK - 1) hfin[(size_t)b * HU + u0 + g_u] = ho_reg;
        }
        __syncthreads();   // barrier 2: gate zp-reads done before next zp write
    }
    if (gl) cst[(size_t)(r0 + g_r) * HU + u0 + g_u] = c_reg;
}

// ---------------------------------------------------------------------------
// Phase 3: logits = h_final @ W_dense + b_dense; log-softmax NLL; mean loss.
// One wave per batch row.
// ---------------------------------------------------------------------------
__global__ __launch_bounds__(64) void cls_kernel(
    const float* __restrict__ hfin, const float* __restrict__ Wd,
    const float* __restrict__ bd, const int* __restrict__ labels,
    float* __restrict__ out)
{
    const int b = blockIdx.x;
    const int ln = threadIdx.x;
    const float* h = hfin + (size_t)b * HU;
    float p0 = 0.f, p1 = 0.f, p2 = 0.f;
    for (int k = ln; k < HU; k += 64) {
        float hv = h[k];
        p0 += hv * Wd[k * 3 + 0];
        p1 += hv * Wd[k * 3 + 1];
        p2 += hv * Wd[k * 3 + 2];
    }
    #pragma unroll
    for (int off = 32; off > 0; off >>= 1) {
        p0 += __shfl_down(p0, off);
        p1 += __shfl_down(p1, off);
        p2 += __shfl_down(p2, off);
    }
    if (ln == 0) {
        float l0 = p0 + bd[0], l1 = p1 + bd[1], l2 = p2 + bd[2];
        float m = fmaxf(l0, fmaxf(l1, l2));
        float lse = m + logf(__expf(l0 - m) + __expf(l1 - m) + __expf(l2 - m));
        int lab = labels[b];
        float sel = (lab == 0) ? l0 : ((lab == 1) ? l1 : l2);
        float nll = lse - sel;
        out[1 + b * 3 + 0] = l0;
        out[1 + b * 3 + 1] = l1;
        out[1 + b * 3 + 2] = l2;
        atomicAdd(out, nll * (1.0f / BB));
    }
}

// ---------------------------------------------------------------------------
extern "C" void kernel_launch(void* const* d_in, const int* in_sizes, int n_in,
                              void* d_out, int out_size, void* d_ws, size_t ws_size,
                              hipStream_t stream) {
    const int*   ids  = (const int*)d_in[0];
    const int*   lens = (const int*)d_in[1];
    const int*   labs = (const int*)d_in[2];
    const float* emb  = (const float*)d_in[3];
    const float* Wl   = (const float*)d_in[4];
    const float* bl   = (const float*)d_in[5];
    const float* Wd   = (const float*)d_in[6];
    const float* bd   = (const float*)d_in[7];
    float* out = (float*)d_out;

    ull*   ex   = (ull*)d_ws;
    float* cst  = (float*)(ex + EX_W);
    float* hfin = cst + CST_F;

    {   // zero exchange tags / c state / out[0]
        int n = (int)((EX_W + 255) / 256);
        init_kernel<<<n, 256, 0, stream>>>(ex, cst, out);
    }
    for (int c = 0; c < NCHUNK; ++c) {
        int t0 = c * CHUNK;
        lstm_rec<<<GR * GC, 256, 0, stream>>>(emb, ids, Wl, bl, lens,
                                              ex, cst, hfin, t0);
    }
    cls_kernel<<<BB, 64, 0, stream>>>(hfin, Wd, bd, labs, out);
}